// Round 1
// 758.349 us; speedup vs baseline: 1.1136x; 1.1136x over previous
//
#include <hip/hip_runtime.h>
#include <hip/hip_bf16.h>
#include <math.h>

// Transformer block: rmsnorm -> fused QK GEMM + V^T GEMM -> rope -> causal flash attn
// -> Wo + residual -> rmsnorm -> SwiGLU MLP -> split-K down-proj + residual.
// v5: big MLP GEMMs (gate/up/down) moved to a 256x256-tile 8-phase schedule
// (T2 XOR-swizzled LDS + T4 counted vmcnt + T5 setprio), down-proj split-K=4.

#define HIDDENC 2048
#define SLEN    2048
#define NHEADS  16
#define NKV     4
#define HD      128
#define INTERC  8192

typedef __attribute__((ext_vector_type(8))) short bf16x8;   // 8 x bf16 (4 VGPRs)
typedef __attribute__((ext_vector_type(4))) float f32x4;
typedef __hip_bfloat16 bf16;

__device__ __forceinline__ void gld_lds16(const void* g, void* l) {
    __builtin_amdgcn_global_load_lds((const __attribute__((address_space(1))) void*)g,
                                     (__attribute__((address_space(3))) void*)l, 16, 0, 0);
}

__device__ __forceinline__ unsigned short bf_bits(float x) {
    bf16 t = __float2bfloat16(x);
    return *(unsigned short*)&t;
}
__device__ __forceinline__ float bits_f(short s) {
    bf16 b = *(bf16*)&s;
    return __bfloat162float(b);
}

#define SBAR      asm volatile("s_barrier" ::: "memory")
#define WAIT_VM4  asm volatile("s_waitcnt vmcnt(4)" ::: "memory")
#define WAIT_VM0  asm volatile("s_waitcnt vmcnt(0)" ::: "memory")

// ---------------- GEMM: C[M][N] = A[M][K'] @ B[N][K']^T, row stride lda -------------
// 128x128 tile, 2-phase. EPI=0: bf16 C.  EPI=1: fp32 C = acc + R.
template <int EPI>
__global__ __launch_bounds__(256) void gemm_bt(const bf16* __restrict__ A,
                                               const bf16* __restrict__ B,
                                               void* __restrict__ Cout,
                                               const float* __restrict__ R,
                                               int M, int N, int K, int lda) {
    constexpr int BM = 128, BN = 128, BK = 64;
    __shared__ bf16 As[BM * BK];
    __shared__ bf16 Bs[BN * BK];
    const int tid  = threadIdx.x;
    const int wave = tid >> 6;
    const int lane = tid & 63;
    const int wm = wave >> 1, wn = wave & 1;        // 2x2 waves, 64x64 each
    const long m0 = (long)blockIdx.y * BM;
    const long n0 = (long)blockIdx.x * BN;

    const int srow = wave * 8 + (lane >> 3);
    const int scol = (lane & 7) * 8;
    const bf16* Ag = A + (m0 + srow) * (long)lda + scol;
    const bf16* Bg = B + (n0 + srow) * (long)lda + scol;
    bf16* Asw = &As[(wave * 8) * BK];
    bf16* Bsw = &Bs[(wave * 8) * BK];

    f32x4 acc[4][4] = {};
    const int row = lane & 15;
    const int kq  = (lane >> 4) * 8;

    for (int k0 = 0; k0 < K; k0 += BK) {
#pragma unroll
        for (int t = 0; t < 4; t++) {
            gld_lds16(Ag + (long)(t * 32) * lda + k0, Asw + t * 32 * BK);
            gld_lds16(Bg + (long)(t * 32) * lda + k0, Bsw + t * 32 * BK);
        }
        __syncthreads();
#pragma unroll
        for (int kk = 0; kk < BK; kk += 32) {
            bf16x8 af[4], bfr[4];
#pragma unroll
            for (int i = 0; i < 4; i++)
                af[i] = *(const bf16x8*)&As[(wm * 64 + i * 16 + row) * BK + kk + kq];
#pragma unroll
            for (int j = 0; j < 4; j++)
                bfr[j] = *(const bf16x8*)&Bs[(wn * 64 + j * 16 + row) * BK + kk + kq];
#pragma unroll
            for (int i = 0; i < 4; i++)
#pragma unroll
                for (int j = 0; j < 4; j++)
                    acc[i][j] = __builtin_amdgcn_mfma_f32_16x16x32_bf16(af[i], bfr[j], acc[i][j], 0, 0, 0);
        }
        __syncthreads();
    }

    const int quad = lane >> 4;
#pragma unroll
    for (int i = 0; i < 4; i++)
#pragma unroll
        for (int j = 0; j < 4; j++)
#pragma unroll
            for (int r = 0; r < 4; r++) {
                long rr = m0 + wm * 64 + i * 16 + quad * 4 + r;   // C/D: row = quad*4+reg
                long cc = n0 + wn * 64 + j * 16 + (lane & 15);    //      col = lane&15
                float v = acc[i][j][r];
                if (EPI == 0) {
                    ((bf16*)Cout)[rr * N + cc] = __float2bfloat16(v);
                } else {
                    ((float*)Cout)[rr * N + cc] = v + R[rr * N + cc];
                }
            }
}

// ---------------- GEMM 256x256, 8-phase counted-vmcnt schedule ----------------------
// C[M][N] = A[M][K'] @ B[N][K']^T (per split-K slice). 512 thr = 2x4 waves, each owns
// a 128x64 output tile. BK=64, dbuf LDS 128 KiB. LDS tiles stored with 16B-granule
// XOR swizzle (g ^ row&7) via pre-swizzled GLOBAL source + linear global_load_lds dest
// (rule #21); ds_read_b128 fragment loads apply the same XOR -> conflict-free.
// Per K-tile: 4 phases, each = {ds_read subtile | stage prefetch | bar | MFMA quadrant
// (16x) under setprio | bar}; vmcnt(4) once per tile (B of tile t+2 stays in flight).
// EPI=0: bf16 C.  EPI=2: fp32 partial at Cout + z*M*N.
template <int EPI>
__global__ __launch_bounds__(512) void gemm256(const bf16* __restrict__ A,
                                               const bf16* __restrict__ B,
                                               void* __restrict__ Cout,
                                               int M, int N, int K, int lda) {
    __shared__ __align__(16) bf16 smem[2][2][256 * 64];   // [dbuf][A=0/B=1][256 rows][64]
    const int tid  = threadIdx.x;
    const int wave = tid >> 6, lane = tid & 63;
    const int wm = wave >> 2, wn = wave & 3;              // 2 x 4 waves
    const int quad = lane >> 4, lrow = lane & 15;
    const long m0 = (long)blockIdx.y * 256;
    const long n0 = (long)blockIdx.x * 256;
    const long kofs = (long)blockIdx.z * K;

    // staging: thread covers (row = rr*64 + srow, one 16B granule). LDS dest is linear
    // (tid*16B); the global source granule is pre-swizzled so the read-side XOR matches.
    const int srow  = tid >> 3;                           // 0..63
    const int gphys = tid & 7;
    const int glog  = gphys ^ (srow & 7);
    const bf16* Ag = A + (m0 + srow) * (long)lda + kofs + glog * 8;
    const bf16* Bg = B + (n0 + srow) * (long)lda + kofs + glog * 8;

    auto stageA = [&](int tt) {                           // full A tile of K-tile tt (4 ld)
#pragma unroll
        for (int rr = 0; rr < 4; rr++)
            gld_lds16(Ag + ((long)tt << 6) + (long)(rr * 64) * lda,
                      &smem[tt & 1][0][tid * 8 + rr * 4096]);
    };
    auto stageB = [&](int tt, int hh) {                   // half B tile (2 ld)
#pragma unroll
        for (int r2 = 0; r2 < 2; r2++) {
            int rr = hh * 2 + r2;
            gld_lds16(Bg + ((long)tt << 6) + (long)(rr * 64) * lda,
                      &smem[tt & 1][1][tid * 8 + rr * 4096]);
        }
    };

    f32x4 acc[8][4] = {};
    const int swz = (quad ^ (lrow & 7)) * 8;              // ks=0 granule elem offset
    const int NT = K >> 6;

    // prologue: A(0)+B(0) must arrive; B(1) (4 loads, newest) stays in flight.
    stageA(0);
    stageB(0, 0); stageB(0, 1);
    if (NT > 1) { stageB(1, 0); stageB(1, 1); }
    WAIT_VM4;
    SBAR;

    for (int t = 0; t < NT; ++t) {
        const bf16* smA = &smem[t & 1][0][0];
        const bf16* smB = &smem[t & 1][1][0];
        bf16x8 bq[4][2], aq[2][2];

        // ---- phase 0: all B frags + A quadrant 0; stage A(t+1) into other buffer ----
#pragma unroll
        for (int n = 0; n < 4; n++)
#pragma unroll
            for (int ks = 0; ks < 2; ks++)
                bq[n][ks] = *(const bf16x8*)&smB[(wn * 64 + n * 16 + lrow) * 64 + (swz ^ (ks * 32))];
#pragma unroll
        for (int i = 0; i < 2; i++)
#pragma unroll
            for (int ks = 0; ks < 2; ks++)
                aq[i][ks] = *(const bf16x8*)&smA[(wm * 128 + i * 16 + lrow) * 64 + (swz ^ (ks * 32))];
        if (t + 1 < NT) stageA(t + 1);
        SBAR;
        __builtin_amdgcn_s_setprio(1);
#pragma unroll
        for (int i = 0; i < 2; i++)
#pragma unroll
            for (int n = 0; n < 4; n++) {
                acc[i][n] = __builtin_amdgcn_mfma_f32_16x16x32_bf16(aq[i][0], bq[n][0], acc[i][n], 0, 0, 0);
                acc[i][n] = __builtin_amdgcn_mfma_f32_16x16x32_bf16(aq[i][1], bq[n][1], acc[i][n], 0, 0, 0);
            }
        __builtin_amdgcn_s_setprio(0);
        SBAR;

        // ---- phases 1..3: A quadrants 1..3; stage B(t+2) halves; boundary vmcnt ----
#pragma unroll
        for (int q = 1; q < 4; q++) {
#pragma unroll
            for (int i = 0; i < 2; i++)
#pragma unroll
                for (int ks = 0; ks < 2; ks++)
                    aq[i][ks] = *(const bf16x8*)&smA[(wm * 128 + (q * 2 + i) * 16 + lrow) * 64 + (swz ^ (ks * 32))];
            if (q == 1) { if (t + 2 < NT) stageB(t + 2, 0); }
            if (q == 2) { if (t + 2 < NT) stageB(t + 2, 1); }
            SBAR;
            __builtin_amdgcn_s_setprio(1);
#pragma unroll
            for (int i = 0; i < 2; i++)
#pragma unroll
                for (int n = 0; n < 4; n++) {
                    acc[q * 2 + i][n] = __builtin_amdgcn_mfma_f32_16x16x32_bf16(aq[i][0], bq[n][0], acc[q * 2 + i][n], 0, 0, 0);
                    acc[q * 2 + i][n] = __builtin_amdgcn_mfma_f32_16x16x32_bf16(aq[i][1], bq[n][1], acc[q * 2 + i][n], 0, 0, 0);
                }
            __builtin_amdgcn_s_setprio(0);
            if (q == 3) {
                if (t + 2 < NT) { WAIT_VM4; } else { WAIT_VM0; }
            }
            SBAR;
        }
    }

    // epilogue: C/D row = quad*4+reg, col = lane&15
#pragma unroll
    for (int i = 0; i < 8; i++)
#pragma unroll
        for (int n = 0; n < 4; n++)
#pragma unroll
            for (int r = 0; r < 4; r++) {
                long rr = m0 + wm * 128 + i * 16 + quad * 4 + r;
                long cc = n0 + wn * 64 + n * 16 + lrow;
                float v = acc[i][n][r];
                if (EPI == 0) {
                    ((bf16*)Cout)[rr * N + cc] = __float2bfloat16(v);
                } else {
                    ((float*)Cout)[(long)blockIdx.z * M * N + rr * N + cc] = v;
                }
            }
}

// ---------------- RMSNorm: one block per row, fp32 in -> bf16 out -------------------
__global__ __launch_bounds__(256) void rmsnorm_kernel(const float* __restrict__ x,
                                                      const float* __restrict__ w,
                                                      bf16* __restrict__ out) {
    const int row = blockIdx.x;
    const int tid = threadIdx.x;
    const float* xr = x + (long)row * HIDDENC;
    float4 a = *(const float4*)&xr[tid * 8];
    float4 b = *(const float4*)&xr[tid * 8 + 4];
    float ss = a.x*a.x + a.y*a.y + a.z*a.z + a.w*a.w + b.x*b.x + b.y*b.y + b.z*b.z + b.w*b.w;
#pragma unroll
    for (int d = 1; d < 64; d <<= 1) ss += __shfl_xor(ss, d, 64);
    __shared__ float wsum[4];
    if ((tid & 63) == 0) wsum[tid >> 6] = ss;
    __syncthreads();
    ss = wsum[0] + wsum[1] + wsum[2] + wsum[3];
    float sc = rsqrtf(ss * (1.0f / HIDDENC) + 1e-6f);
    float4 wa = *(const float4*)&w[tid * 8];
    float4 wb = *(const float4*)&w[tid * 8 + 4];
    float vals[8] = {a.x*wa.x, a.y*wa.y, a.z*wa.z, a.w*wa.w,
                     b.x*wb.x, b.y*wb.y, b.z*wb.z, b.w*wb.w};
    union { bf16x8 v; unsigned short u[8]; } pk;
#pragma unroll
    for (int e = 0; e < 8; e++) pk.u[e] = bf_bits(vals[e] * sc);
    *(bf16x8*)&out[(long)row * HIDDENC + tid * 8] = pk.v;
}

// ---------------- fp32 -> bf16 convert (weights) ------------------------------------
__global__ __launch_bounds__(256) void cvt_kernel(const float* __restrict__ in,
                                                  bf16* __restrict__ out, long n) {
    long idx = ((long)blockIdx.x * 256 + threadIdx.x) * 8;
    if (idx >= n) return;
    float4 a = *(const float4*)&in[idx];
    float4 b = *(const float4*)&in[idx + 4];
    float vals[8] = {a.x, a.y, a.z, a.w, b.x, b.y, b.z, b.w};
    union { bf16x8 v; unsigned short u[8]; } pk;
#pragma unroll
    for (int e = 0; e < 8; e++) pk.u[e] = bf_bits(vals[e]);
    *(bf16x8*)&out[idx] = pk.v;
}

// ---------------- RoPE in-place on bf16 [S][rowstride], heads at col h*HD -----------
__global__ __launch_bounds__(256) void rope_kernel(bf16* __restrict__ x,
                                                   const int* __restrict__ pos,
                                                   int nheads, int rowstride) {
    long gid = (long)blockIdx.x * 256 + threadIdx.x;
    int i = gid & 63;
    long t = gid >> 6;
    int h = (int)(t % nheads);
    long s = t / nheads;
    if (s >= SLEN) return;
    float inv = __expf(-(float)i * 0.14391156516779195f);   // ln(10000)/64
    float f = (float)pos[s] * inv;
    float sn, c;
    sincosf(f, &sn, &c);
    bf16* p = x + s * (long)rowstride + h * HD + i;
    float x1 = __bfloat162float(p[0]);
    float x2 = __bfloat162float(p[64]);
    p[0]  = __float2bfloat16(x1 * c - x2 * sn);
    p[64] = __float2bfloat16(x2 * c + x1 * sn);
}

// ---------------- causal flash attention v4 -----------------------------------------
// grid (32 qtiles, 16 heads) = 512 blocks; qt = 31-bx (heavy first). 4 waves x 16
// q-rows. Per kt: cooperative stage of K tile [64][128] and V^T tile [128][64] into
// LDS with XOR-swizzled 16B granules (conflict-free writes AND fragment reads).
__global__ __launch_bounds__(256) void flash_attn(const bf16* __restrict__ Q,   // [S][2560]
                                                  const bf16* __restrict__ Kb,  // +2048 col
                                                  const bf16* __restrict__ VT,  // [512][2048]
                                                  bf16* __restrict__ Ctx) {     // [S][2048]
    constexpr int QSTR = 2560, PSTR = 68, BKEY = 64;
    __shared__ bf16 Ks[64 * 128];                   // swizzled [key][d], 16 KB
    __shared__ bf16 Vs[128 * 64];                   // swizzled [d][key], 16 KB
    __shared__ bf16 Ps[4][16 * PSTR];               // per-wave P [16 q][64 keys + pad]
    const int qt  = 31 - blockIdx.x;                // heavy tiles dispatched first
    const int h   = blockIdx.y;
    const int kvh = h >> 2;
    const int tid = threadIdx.x;
    const int wave = tid >> 6, lane = tid & 63;
    const int quad = lane >> 4, lrow = lane & 15;
    const int qbase = qt * 64 + wave * 16;

    // resident Q fragments (A-layout: m=lane&15, k=quad*8+e)
    bf16x8 qf[4];
#pragma unroll
    for (int kk = 0; kk < 4; kk++)
        qf[kk] = *(const bf16x8*)&Q[(long)(qbase + lrow) * QSTR + h * HD + kk * 32 + quad * 8];

    f32x4 o[8] = {};
    float mrow[4], lsum[4];
#pragma unroll
    for (int r = 0; r < 4; r++) { mrow[r] = -1e30f; lsum[r] = 0.0f; }

    const int nkt = qt + 1;                         // keys < (qt+1)*64
    const float scale = 0.08838834764831845f;       // 1/sqrt(128)
    const bf16* Kh  = Kb + kvh * HD;                // [key][2560]
    const bf16* VTh = VT + (long)(kvh * HD) * SLEN; // [128][2048]
    bf16* Pw = Ps[wave];

    for (int kt = 0; kt < nkt; kt++) {
        __syncthreads();                            // guard Ks/Vs reuse
        // stage K tile [64 keys][128 d]: granule g (16B) -> g ^ (row & 15)
#pragma unroll
        for (int rd = 0; rd < 4; rd++) {
            int id = rd * 256 + tid;
            int row = id >> 4, g = id & 15;
            bf16x8 kv = *(const bf16x8*)&Kh[(long)(kt * BKEY + row) * QSTR + g * 8];
            *(bf16x8*)&Ks[row * 128 + ((g ^ (row & 15)) * 8)] = kv;
        }
        // stage V^T tile [128 d][64 keys]: granule g (16B) -> g ^ (d & 7)
#pragma unroll
        for (int rd = 0; rd < 4; rd++) {
            int id = rd * 256 + tid;
            int d = id >> 3, g = id & 7;
            bf16x8 vv = *(const bf16x8*)&VTh[(long)d * SLEN + kt * BKEY + g * 8];
            *(bf16x8*)&Vs[d * 64 + ((g ^ (d & 7)) * 8)] = vv;
        }
        __syncthreads();

        // S = Q K^T : K fragments from swizzled LDS (B-layout: n=key on lanes)
        f32x4 sacc[4] = {};
#pragma unroll
        for (int kk = 0; kk < 4; kk++) {
            bf16x8 kb[4];
#pragma unroll
            for (int j = 0; j < 4; j++)
                kb[j] = *(const bf16x8*)&Ks[(j * 16 + lrow) * 128 + (((kk * 4 + quad) ^ lrow) * 8)];
#pragma unroll
            for (int j = 0; j < 4; j++)
                sacc[j] = __builtin_amdgcn_mfma_f32_16x16x32_bf16(qf[kk], kb[j], sacc[j], 0, 0, 0);
        }

        // scale + causal mask (only the diagonal tile kt==qt)
        const bool diag = (kt == qt);
#pragma unroll
        for (int j = 0; j < 4; j++)
#pragma unroll
            for (int r = 0; r < 4; r++) {
                float v = sacc[j][r] * scale;
                if (diag) {
                    int rowg = qbase + quad * 4 + r;
                    int colg = qt * 64 + j * 16 + lrow;
                    if (colg > rowg) v = -1e30f;
                }
                sacc[j][r] = v;
            }

        // online softmax per q-row (row lives on 16 lanes sharing quad)
        float alpha[4];
#pragma unroll
        for (int r = 0; r < 4; r++) {
            float mx = sacc[0][r];
#pragma unroll
            for (int j = 1; j < 4; j++) mx = fmaxf(mx, sacc[j][r]);
#pragma unroll
            for (int d = 1; d < 16; d <<= 1) mx = fmaxf(mx, __shfl_xor(mx, d, 16));
            float mnew = fmaxf(mrow[r], mx);
            float a = __expf(mrow[r] - mnew);
            mrow[r] = mnew;
            alpha[r] = a;
            float rs = 0.0f;
#pragma unroll
            for (int j = 0; j < 4; j++) {
                float p = __expf(sacc[j][r] - mnew);
                sacc[j][r] = p;
                rs += p;
            }
#pragma unroll
            for (int d = 1; d < 16; d <<= 1) rs += __shfl_xor(rs, d, 16);
            lsum[r] = lsum[r] * a + rs;
        }

        // rescale O
#pragma unroll
        for (int dj = 0; dj < 8; dj++)
#pragma unroll
            for (int r = 0; r < 4; r++) o[dj][r] *= alpha[r];

        // P (C-layout) -> per-wave LDS (conflict-free) -> A-operand fragments
#pragma unroll
        for (int j = 0; j < 4; j++)
#pragma unroll
            for (int r = 0; r < 4; r++)
                Pw[(quad * 4 + r) * PSTR + j * 16 + lrow] = __float2bfloat16(sacc[j][r]);
        __asm__ volatile("s_waitcnt lgkmcnt(0)" ::: "memory");   // same-wave write->read

        // O += P V : V^T fragments from swizzled LDS (B-layout: n=d on lanes)
#pragma unroll
        for (int kk = 0; kk < 2; kk++) {
            bf16x8 pf = *(const bf16x8*)&Pw[lrow * PSTR + kk * 32 + quad * 8];
#pragma unroll
            for (int dj = 0; dj < 8; dj++) {
                int dr = dj * 16 + lrow;
                bf16x8 vb = *(const bf16x8*)&Vs[dr * 64 + (((kk * 4 + quad) ^ (dr & 7)) * 8)];
                o[dj] = __builtin_amdgcn_mfma_f32_16x16x32_bf16(pf, vb, o[dj], 0, 0, 0);
            }
        }
    }

    // epilogue: ctx[s][h*128 + d] = O / lsum
#pragma unroll
    for (int dj = 0; dj < 8; dj++)
#pragma unroll
        for (int r = 0; r < 4; r++) {
            long rowg = qbase + quad * 4 + r;
            long col  = (long)h * HD + dj * 16 + lrow;
            Ctx[rowg * (NHEADS * HD) + col] = __float2bfloat16(o[dj][r] / lsum[r]);
        }
}

// ---------------- SwiGLU elementwise: act = silu(gate) * up (bf16) ------------------
__global__ __launch_bounds__(256) void silu_mul_kernel(const bf16* __restrict__ g,
                                                       const bf16* __restrict__ u,
                                                       bf16* __restrict__ out, long n) {
    long idx = ((long)blockIdx.x * 256 + threadIdx.x) * 8;
    if (idx >= n) return;
    bf16x8 gv = *(const bf16x8*)&g[idx];
    bf16x8 uv = *(const bf16x8*)&u[idx];
    union { bf16x8 v; unsigned short w[8]; } pk;
#pragma unroll
    for (int e = 0; e < 8; e++) {
        float gf = bits_f(gv[e]);
        float uf = bits_f(uv[e]);
        float s = gf / (1.0f + __expf(-gf));
        pk.w[e] = bf_bits(s * uf);
    }
    *(bf16x8*)&out[idx] = pk.v;
}

// ---------------- split-K reduce: out += p0+p1+p2+p3 (residual already in out) ------
__global__ __launch_bounds__(256) void reduce4_kernel(const float* __restrict__ p,
                                                      float* __restrict__ out, long n) {
    long idx = ((long)blockIdx.x * 256 + threadIdx.x) * 4;
    if (idx >= n) return;
    float4 a = *(const float4*)&p[idx];
    float4 b = *(const float4*)&p[idx + n];
    float4 c = *(const float4*)&p[idx + 2 * n];
    float4 d = *(const float4*)&p[idx + 3 * n];
    float4 o = *(const float4*)&out[idx];
    o.x += a.x + b.x + c.x + d.x;
    o.y += a.y + b.y + c.y + d.y;
    o.z += a.z + b.z + c.z + d.z;
    o.w += a.w + b.w + c.w + d.w;
    *(float4*)&out[idx] = o;
}

// ------------------------------------------------------------------------------------
extern "C" void kernel_launch(void* const* d_in, const int* in_sizes, int n_in,
                              void* d_out, int out_size, void* d_ws, size_t ws_size,
                              hipStream_t stream) {
    const float* hidden = (const float*)d_in[0];
    const int*   pos    = (const int*)d_in[2];
    const float* n1w    = (const float*)d_in[3];
    const float* n2w    = (const float*)d_in[4];
    const float* Wq     = (const float*)d_in[5];
    const float* Wk     = (const float*)d_in[6];
    const float* Wv     = (const float*)d_in[7];
    const float* Wo     = (const float*)d_in[8];
    const float* Wg     = (const float*)d_in[9];
    const float* Wu     = (const float*)d_in[10];
    const float* Wd     = (const float*)d_in[11];
    float* out = (float*)d_out;

    char* ws = (char*)d_ws;
    const size_t MB = 1ull << 20;
    // Phase A:
    bf16* h    = (bf16*)(ws + 0);        // 8 MB  (also h2)
    bf16* qk   = (bf16*)(ws + 8  * MB);  // 10 MB [2048][2560] = q|k
    bf16* vt   = (bf16*)(ws + 18 * MB);  // 2 MB  [512][2048]  = V^T
    bf16* ctx  = (bf16*)(ws + 20 * MB);  // 8 MB
    bf16* wqk  = (bf16*)(ws + 28 * MB);  // 10 MB [2560][2048]; reused for wob (8 MB)
    bf16* wvb  = (bf16*)(ws + 38 * MB);  // 2 MB  [512][2048]
    // Phase B (reuses phase-A space once dead):
    bf16*  wg   = (bf16*)(ws + 8   * MB); // 32 MB
    bf16*  wu   = (bf16*)(ws + 40  * MB); // 32 MB
    bf16*  gate = (bf16*)(ws + 72  * MB); // 32 MB (silu writes act in-place)
    bf16*  up   = (bf16*)(ws + 104 * MB); // 32 MB
    bf16*  wd   = (bf16*)(ws + 104 * MB); // 32 MB (reuses up after silu)
    float* pbuf = (float*)(ws + 0);       // 67 MB (4 x 16.8 MB split-K partials;
                                          //        h/qk/wg/wu all dead by down-proj)
    bf16* wob = wqk;

    // 1) rmsnorm1 -> h
    rmsnorm_kernel<<<dim3(2048), dim3(256), 0, stream>>>(hidden, n1w, h);
    // 2) convert Wq|Wk into [2560][2048], Wv into its own block
    cvt_kernel<<<dim3(2048), dim3(256), 0, stream>>>(Wq, wqk,                2048L * 2048);
    cvt_kernel<<<dim3(512),  dim3(256), 0, stream>>>(Wk, wqk + 2048L * 2048, 512L * 2048);
    cvt_kernel<<<dim3(512),  dim3(256), 0, stream>>>(Wv, wvb,                512L * 2048);
    // 3) fused QK projection -> qk [2048][2560];  V^T = Wv @ h^T -> vt [512][2048]
    gemm_bt<0><<<dim3(20, 16), dim3(256), 0, stream>>>(h, wqk, qk, nullptr, 2048, 2560, 2048, 2048);
    gemm_bt<0><<<dim3(16, 4),  dim3(256), 0, stream>>>(wvb, h, vt, nullptr, 512, 2048, 2048, 2048);
    // 4) rope on q (cols 0..2047) and k (cols 2048..2559)
    rope_kernel<<<dim3(8192), dim3(256), 0, stream>>>(qk, pos, NHEADS, 2560);
    rope_kernel<<<dim3(2048), dim3(256), 0, stream>>>(qk + 2048, pos, NKV, 2560);
    // 5) flash attention -> ctx
    flash_attn<<<dim3(32, 16), dim3(256), 0, stream>>>(qk, qk + 2048, vt, ctx);
    // 6) Wo projection + residual -> out (fp32)
    cvt_kernel<<<dim3(2048), dim3(256), 0, stream>>>(Wo, wob, 2048L * 2048);
    gemm_bt<1><<<dim3(16, 16), dim3(256), 0, stream>>>(ctx, wob, out, hidden, 2048, 2048, 2048, 2048);
    // 7) rmsnorm2 -> h
    rmsnorm_kernel<<<dim3(2048), dim3(256), 0, stream>>>(out, n2w, h);
    // 8) MLP: big GEMMs on the 256x256 8-phase kernel (256 blocks each = 1/CU)
    cvt_kernel<<<dim3(8192), dim3(256), 0, stream>>>(Wg, wg, 8192L * 2048);
    cvt_kernel<<<dim3(8192), dim3(256), 0, stream>>>(Wu, wu, 8192L * 2048);
    gemm256<0><<<dim3(32, 8), dim3(512), 0, stream>>>(h, wg, gate, 2048, 8192, 2048, 2048);
    gemm256<0><<<dim3(32, 8), dim3(512), 0, stream>>>(h, wu, up,   2048, 8192, 2048, 2048);
    silu_mul_kernel<<<dim3(8192), dim3(256), 0, stream>>>(gate, up, gate, 2048L * 8192);
    cvt_kernel<<<dim3(8192), dim3(256), 0, stream>>>(Wd, wd, 2048L * 8192);
    // 9) down-proj split-K=4 (8x8x4 = 256 blocks) -> fp32 partials, then out += sum
    gemm256<2><<<dim3(8, 8, 4), dim3(512), 0, stream>>>(gate, wd, pbuf, 2048, 2048, 2048, 8192);
    reduce4_kernel<<<dim3(4096), dim3(256), 0, stream>>>(pbuf, out, 2048L * 2048);
    (void)in_sizes; (void)n_in; (void)out_size; (void)ws_size;
}

// Round 3
// 735.026 us; speedup vs baseline: 1.1490x; 1.0317x over previous
//
#include <hip/hip_runtime.h>
#include <hip/hip_bf16.h>
#include <math.h>

// Transformer block: rmsnorm -> fused QK GEMM + V^T GEMM -> rope -> causal flash attn
// (v5: key-split flash-decoding, dbuf global_load_lds staging, combine kernel)
// -> Wo + residual -> rmsnorm -> SwiGLU MLP (silu fused into up-GEMM epilogue)
// -> split-K down-proj + residual.

#define HIDDENC 2048
#define SLEN    2048
#define NHEADS  16
#define NKV     4
#define HD      128
#define INTERC  8192

typedef __attribute__((ext_vector_type(8))) short bf16x8;   // 8 x bf16 (4 VGPRs)
typedef __attribute__((ext_vector_type(4))) float f32x4;
typedef __hip_bfloat16 bf16;

__device__ __forceinline__ void gld_lds16(const void* g, void* l) {
    __builtin_amdgcn_global_load_lds((const __attribute__((address_space(1))) void*)g,
                                     (__attribute__((address_space(3))) void*)l, 16, 0, 0);
}

__device__ __forceinline__ unsigned short bf_bits(float x) {
    bf16 t = __float2bfloat16(x);
    return *(unsigned short*)&t;
}
__device__ __forceinline__ float bits_f(short s) {
    bf16 b = *(bf16*)&s;
    return __bfloat162float(b);
}

#define SBAR      asm volatile("s_barrier" ::: "memory")
#define WAIT_VM4  asm volatile("s_waitcnt vmcnt(4)" ::: "memory")
#define WAIT_VM0  asm volatile("s_waitcnt vmcnt(0)" ::: "memory")

// ---------------- GEMM: C[M][N] = A[M][K'] @ B[N][K']^T, row stride lda -------------
// 128x128 tile, 2-phase. EPI=0: bf16 C.  EPI=1: fp32 C = acc + R.
template <int EPI>
__global__ __launch_bounds__(256) void gemm_bt(const bf16* __restrict__ A,
                                               const bf16* __restrict__ B,
                                               void* __restrict__ Cout,
                                               const float* __restrict__ R,
                                               int M, int N, int K, int lda) {
    constexpr int BM = 128, BN = 128, BK = 64;
    __shared__ bf16 As[BM * BK];
    __shared__ bf16 Bs[BN * BK];
    const int tid  = threadIdx.x;
    const int wave = tid >> 6;
    const int lane = tid & 63;
    const int wm = wave >> 1, wn = wave & 1;        // 2x2 waves, 64x64 each
    const long m0 = (long)blockIdx.y * BM;
    const long n0 = (long)blockIdx.x * BN;

    const int srow = wave * 8 + (lane >> 3);
    const int scol = (lane & 7) * 8;
    const bf16* Ag = A + (m0 + srow) * (long)lda + scol;
    const bf16* Bg = B + (n0 + srow) * (long)lda + scol;
    bf16* Asw = &As[(wave * 8) * BK];
    bf16* Bsw = &Bs[(wave * 8) * BK];

    f32x4 acc[4][4] = {};
    const int row = lane & 15;
    const int kq  = (lane >> 4) * 8;

    for (int k0 = 0; k0 < K; k0 += BK) {
#pragma unroll
        for (int t = 0; t < 4; t++) {
            gld_lds16(Ag + (long)(t * 32) * lda + k0, Asw + t * 32 * BK);
            gld_lds16(Bg + (long)(t * 32) * lda + k0, Bsw + t * 32 * BK);
        }
        __syncthreads();
#pragma unroll
        for (int kk = 0; kk < BK; kk += 32) {
            bf16x8 af[4], bfr[4];
#pragma unroll
            for (int i = 0; i < 4; i++)
                af[i] = *(const bf16x8*)&As[(wm * 64 + i * 16 + row) * BK + kk + kq];
#pragma unroll
            for (int j = 0; j < 4; j++)
                bfr[j] = *(const bf16x8*)&Bs[(wn * 64 + j * 16 + row) * BK + kk + kq];
#pragma unroll
            for (int i = 0; i < 4; i++)
#pragma unroll
                for (int j = 0; j < 4; j++)
                    acc[i][j] = __builtin_amdgcn_mfma_f32_16x16x32_bf16(af[i], bfr[j], acc[i][j], 0, 0, 0);
        }
        __syncthreads();
    }

    const int quad = lane >> 4;
#pragma unroll
    for (int i = 0; i < 4; i++)
#pragma unroll
        for (int j = 0; j < 4; j++)
#pragma unroll
            for (int r = 0; r < 4; r++) {
                long rr = m0 + wm * 64 + i * 16 + quad * 4 + r;   // C/D: row = quad*4+reg
                long cc = n0 + wn * 64 + j * 16 + (lane & 15);    //      col = lane&15
                float v = acc[i][j][r];
                if (EPI == 0) {
                    ((bf16*)Cout)[rr * N + cc] = __float2bfloat16(v);
                } else {
                    ((float*)Cout)[rr * N + cc] = v + R[rr * N + cc];
                }
            }
}

// ---------------- GEMM 256x256, 8-phase counted-vmcnt schedule ----------------------
// C[M][N] = A[M][K'] @ B[N][K']^T (per split-K slice). 512 thr = 2x4 waves, each owns
// a 128x64 output tile. BK=64, dbuf LDS 128 KiB. LDS tiles stored with 16B-granule
// XOR swizzle (g ^ row&7) via pre-swizzled GLOBAL source + linear global_load_lds dest
// (rule #21); ds_read_b128 fragment loads apply the same XOR -> conflict-free.
// Per K-tile: 4 phases, each = {ds_read subtile | stage prefetch | bar | MFMA quadrant
// (16x) under setprio | bar}; vmcnt(4) once per tile (B of tile t+2 stays in flight).
// EPI=0: bf16 C.  EPI=2: fp32 partial at Cout + z*M*N.  EPI=3: bf16 silu(G)*acc.
template <int EPI>
__global__ __launch_bounds__(512) void gemm256(const bf16* __restrict__ A,
                                               const bf16* __restrict__ B,
                                               void* __restrict__ Cout,
                                               const bf16* __restrict__ Gg,
                                               int M, int N, int K, int lda) {
    __shared__ __align__(16) bf16 smem[2][2][256 * 64];   // [dbuf][A=0/B=1][256 rows][64]
    const int tid  = threadIdx.x;
    const int wave = tid >> 6, lane = tid & 63;
    const int wm = wave >> 2, wn = wave & 3;              // 2 x 4 waves
    const int quad = lane >> 4, lrow = lane & 15;
    const long m0 = (long)blockIdx.y * 256;
    const long n0 = (long)blockIdx.x * 256;
    const long kofs = (long)blockIdx.z * K;

    // staging: thread covers (row = rr*64 + srow, one 16B granule). LDS dest is linear
    // (tid*16B); the global source granule is pre-swizzled so the read-side XOR matches.
    const int srow  = tid >> 3;                           // 0..63
    const int gphys = tid & 7;
    const int glog  = gphys ^ (srow & 7);
    const bf16* Ag = A + (m0 + srow) * (long)lda + kofs + glog * 8;
    const bf16* Bg = B + (n0 + srow) * (long)lda + kofs + glog * 8;

    auto stageA = [&](int tt) {                           // full A tile of K-tile tt (4 ld)
#pragma unroll
        for (int rr = 0; rr < 4; rr++)
            gld_lds16(Ag + ((long)tt << 6) + (long)(rr * 64) * lda,
                      &smem[tt & 1][0][tid * 8 + rr * 4096]);
    };
    auto stageB = [&](int tt, int hh) {                   // half B tile (2 ld)
#pragma unroll
        for (int r2 = 0; r2 < 2; r2++) {
            int rr = hh * 2 + r2;
            gld_lds16(Bg + ((long)tt << 6) + (long)(rr * 64) * lda,
                      &smem[tt & 1][1][tid * 8 + rr * 4096]);
        }
    };

    f32x4 acc[8][4] = {};
    const int swz = (quad ^ (lrow & 7)) * 8;              // ks=0 granule elem offset
    const int NT = K >> 6;

    // prologue: A(0)+B(0) must arrive; B(1) (4 loads, newest) stays in flight.
    stageA(0);
    stageB(0, 0); stageB(0, 1);
    if (NT > 1) { stageB(1, 0); stageB(1, 1); }
    WAIT_VM4;
    SBAR;

    for (int t = 0; t < NT; ++t) {
        const bf16* smA = &smem[t & 1][0][0];
        const bf16* smB = &smem[t & 1][1][0];
        bf16x8 bq[4][2], aq[2][2];

        // ---- phase 0: all B frags + A quadrant 0; stage A(t+1) into other buffer ----
#pragma unroll
        for (int n = 0; n < 4; n++)
#pragma unroll
            for (int ks = 0; ks < 2; ks++)
                bq[n][ks] = *(const bf16x8*)&smB[(wn * 64 + n * 16 + lrow) * 64 + (swz ^ (ks * 32))];
#pragma unroll
        for (int i = 0; i < 2; i++)
#pragma unroll
            for (int ks = 0; ks < 2; ks++)
                aq[i][ks] = *(const bf16x8*)&smA[(wm * 128 + i * 16 + lrow) * 64 + (swz ^ (ks * 32))];
        if (t + 1 < NT) stageA(t + 1);
        SBAR;
        __builtin_amdgcn_s_setprio(1);
#pragma unroll
        for (int i = 0; i < 2; i++)
#pragma unroll
            for (int n = 0; n < 4; n++) {
                acc[i][n] = __builtin_amdgcn_mfma_f32_16x16x32_bf16(aq[i][0], bq[n][0], acc[i][n], 0, 0, 0);
                acc[i][n] = __builtin_amdgcn_mfma_f32_16x16x32_bf16(aq[i][1], bq[n][1], acc[i][n], 0, 0, 0);
            }
        __builtin_amdgcn_s_setprio(0);
        SBAR;

        // ---- phases 1..3: A quadrants 1..3; stage B(t+2) halves; boundary vmcnt ----
#pragma unroll
        for (int q = 1; q < 4; q++) {
#pragma unroll
            for (int i = 0; i < 2; i++)
#pragma unroll
                for (int ks = 0; ks < 2; ks++)
                    aq[i][ks] = *(const bf16x8*)&smA[(wm * 128 + (q * 2 + i) * 16 + lrow) * 64 + (swz ^ (ks * 32))];
            if (q == 1) { if (t + 2 < NT) stageB(t + 2, 0); }
            if (q == 2) { if (t + 2 < NT) stageB(t + 2, 1); }
            SBAR;
            __builtin_amdgcn_s_setprio(1);
#pragma unroll
            for (int i = 0; i < 2; i++)
#pragma unroll
                for (int n = 0; n < 4; n++) {
                    acc[q * 2 + i][n] = __builtin_amdgcn_mfma_f32_16x16x32_bf16(aq[i][0], bq[n][0], acc[q * 2 + i][n], 0, 0, 0);
                    acc[q * 2 + i][n] = __builtin_amdgcn_mfma_f32_16x16x32_bf16(aq[i][1], bq[n][1], acc[q * 2 + i][n], 0, 0, 0);
                }
            __builtin_amdgcn_s_setprio(0);
            if (q == 3) {
                if (t + 2 < NT) { WAIT_VM4; } else { WAIT_VM0; }
            }
            SBAR;
        }
    }

    // epilogue: C/D row = quad*4+reg, col = lane&15
#pragma unroll
    for (int i = 0; i < 8; i++)
#pragma unroll
        for (int n = 0; n < 4; n++)
#pragma unroll
            for (int r = 0; r < 4; r++) {
                long rr = m0 + wm * 128 + i * 16 + quad * 4 + r;
                long cc = n0 + wn * 64 + n * 16 + lrow;
                float v = acc[i][n][r];
                if (EPI == 0) {
                    ((bf16*)Cout)[rr * N + cc] = __float2bfloat16(v);
                } else if (EPI == 2) {
                    ((float*)Cout)[(long)blockIdx.z * M * N + rr * N + cc] = v;
                } else {                                  // EPI==3: act = silu(gate)*up
                    float g = __bfloat162float(Gg[rr * N + cc]);
                    float sg = g / (1.0f + __expf(-g));
                    ((bf16*)Cout)[rr * N + cc] = __float2bfloat16(sg * v);
                }
            }
}

// ---------------- RMSNorm: one block per row, fp32 in -> bf16 out -------------------
__global__ __launch_bounds__(256) void rmsnorm_kernel(const float* __restrict__ x,
                                                      const float* __restrict__ w,
                                                      bf16* __restrict__ out) {
    const int row = blockIdx.x;
    const int tid = threadIdx.x;
    const float* xr = x + (long)row * HIDDENC;
    float4 a = *(const float4*)&xr[tid * 8];
    float4 b = *(const float4*)&xr[tid * 8 + 4];
    float ss = a.x*a.x + a.y*a.y + a.z*a.z + a.w*a.w + b.x*b.x + b.y*b.y + b.z*b.z + b.w*b.w;
#pragma unroll
    for (int d = 1; d < 64; d <<= 1) ss += __shfl_xor(ss, d, 64);
    __shared__ float wsum[4];
    if ((tid & 63) == 0) wsum[tid >> 6] = ss;
    __syncthreads();
    ss = wsum[0] + wsum[1] + wsum[2] + wsum[3];
    float sc = rsqrtf(ss * (1.0f / HIDDENC) + 1e-6f);
    float4 wa = *(const float4*)&w[tid * 8];
    float4 wb = *(const float4*)&w[tid * 8 + 4];
    float vals[8] = {a.x*wa.x, a.y*wa.y, a.z*wa.z, a.w*wa.w,
                     b.x*wb.x, b.y*wb.y, b.z*wb.z, b.w*wb.w};
    union { bf16x8 v; unsigned short u[8]; } pk;
#pragma unroll
    for (int e = 0; e < 8; e++) pk.u[e] = bf_bits(vals[e] * sc);
    *(bf16x8*)&out[(long)row * HIDDENC + tid * 8] = pk.v;
}

// ---------------- fp32 -> bf16 convert (weights) ------------------------------------
__global__ __launch_bounds__(256) void cvt_kernel(const float* __restrict__ in,
                                                  bf16* __restrict__ out, long n) {
    long idx = ((long)blockIdx.x * 256 + threadIdx.x) * 8;
    if (idx >= n) return;
    float4 a = *(const float4*)&in[idx];
    float4 b = *(const float4*)&in[idx + 4];
    float vals[8] = {a.x, a.y, a.z, a.w, b.x, b.y, b.z, b.w};
    union { bf16x8 v; unsigned short u[8]; } pk;
#pragma unroll
    for (int e = 0; e < 8; e++) pk.u[e] = bf_bits(vals[e]);
    *(bf16x8*)&out[idx] = pk.v;
}

// ---------------- RoPE in-place on bf16 [S][rowstride], heads at col h*HD -----------
__global__ __launch_bounds__(256) void rope_kernel(bf16* __restrict__ x,
                                                   const int* __restrict__ pos,
                                                   int nheads, int rowstride) {
    long gid = (long)blockIdx.x * 256 + threadIdx.x;
    int i = gid & 63;
    long t = gid >> 6;
    int h = (int)(t % nheads);
    long s = t / nheads;
    if (s >= SLEN) return;
    float inv = __expf(-(float)i * 0.14391156516779195f);   // ln(10000)/64
    float f = (float)pos[s] * inv;
    float sn, c;
    sincosf(f, &sn, &c);
    bf16* p = x + s * (long)rowstride + h * HD + i;
    float x1 = __bfloat162float(p[0]);
    float x2 = __bfloat162float(p[64]);
    p[0]  = __float2bfloat16(x1 * c - x2 * sn);
    p[64] = __float2bfloat16(x2 * c + x1 * sn);
}

// ---------------- causal flash attention v5 (key-split + dbuf gld_lds) --------------
// grid (64, 16): bx -> (qt = 31-(bx>>1), s = bx&1), heavy first. Block handles kt = s,
// s+2, ... <= qt (alternating key tiles) -> partial O (fp32, un-normalized) + (m, l).
// Staging via global_load_lds into double-buffered LDS with pre-swizzled global source
// (linear LDS dest, XOR-granule read swizzle unchanged). Next tile's loads issue before
// this tile's compute -> HBM/L2 latency hides under QK/softmax/PV.
__global__ __launch_bounds__(256) void flash_attn(const bf16* __restrict__ Q,   // [S][2560]
                                                  const bf16* __restrict__ Kb,  // +2048 col
                                                  const bf16* __restrict__ VT,  // [512][2048]
                                                  float* __restrict__ Opart,    // [2][S][2048]
                                                  float* __restrict__ Ml) {     // [2][S][16][2]
    constexpr int QSTR = 2560, PSTR = 68, BKEY = 64;
    __shared__ bf16 Ks[2][64 * 128];                // swizzled [key][d], 2 x 16 KB
    __shared__ bf16 Vs[2][128 * 64];                // swizzled [d][key], 2 x 16 KB
    __shared__ bf16 Ps[4][16 * PSTR];               // per-wave P [16 q][64 keys + pad]
    const int qt  = 31 - (int)(blockIdx.x >> 1);    // heavy tiles dispatched first
    const int sp  = blockIdx.x & 1;                 // key split
    const int h   = blockIdx.y;
    const int kvh = h >> 2;
    const int tid = threadIdx.x;
    const int wave = tid >> 6, lane = tid & 63;
    const int quad = lane >> 4, lrow = lane & 15;
    const int qbase = qt * 64 + wave * 16;

    // resident Q fragments (A-layout: m=lane&15, k=quad*8+e)
    bf16x8 qf[4];
#pragma unroll
    for (int kk = 0; kk < 4; kk++)
        qf[kk] = *(const bf16x8*)&Q[(long)(qbase + lrow) * QSTR + h * HD + kk * 32 + quad * 8];

    f32x4 o[8] = {};
    float mrow[4], lsum[4];
#pragma unroll
    for (int r = 0; r < 4; r++) { mrow[r] = -1e30f; lsum[r] = 0.0f; }

    const float scale = 0.08838834764831845f;       // 1/sqrt(128)
    const bf16* Kh  = Kb + kvh * HD;                // [key][2560]
    const bf16* VTh = VT + (long)(kvh * HD) * SLEN; // [128][2048]
    bf16* Pw = Ps[wave];

    // staging geometry (16B granules, linear LDS dest = id*16B, pre-swizzled source):
    // K: id = rd*256+tid; row = rd*16 + (tid>>4); g = tid&15; glog = g ^ (row&15)
    // V: id = rd*256+tid; d   = rd*32 + (tid>>3); g = tid&7;  glog = g ^ (d&7)
    const int glogK = (tid & 15) ^ ((tid >> 4) & 15);
    const int glogV = (tid & 7) ^ ((tid >> 3) & 7);
    const bf16* KgB = Kh + (long)(tid >> 4) * QSTR + glogK * 8;
    const bf16* VgB = VTh + (long)(tid >> 3) * SLEN + glogV * 8;

    auto stage = [&](int kt, int b) {
#pragma unroll
        for (int rd = 0; rd < 4; rd++)
            gld_lds16(KgB + (long)(kt * BKEY + rd * 16) * QSTR,
                      &Ks[b][(rd * 256 + tid) * 8]);
#pragma unroll
        for (int rd = 0; rd < 4; rd++)
            gld_lds16(VgB + (long)(rd * 32) * SLEN + kt * BKEY,
                      &Vs[b][(rd * 256 + tid) * 8]);
    };

    int cur = 0;
    stage(sp, 0);
    WAIT_VM0;
    __syncthreads();

    for (int kt = sp; kt <= qt; kt += 2) {
        if (kt + 2 <= qt) stage(kt + 2, cur ^ 1);   // prefetch; latency hides under compute

        // S = Q K^T : K fragments from swizzled LDS (B-layout: n=key on lanes)
        f32x4 sacc[4] = {};
        __builtin_amdgcn_s_setprio(1);
#pragma unroll
        for (int kk = 0; kk < 4; kk++) {
            bf16x8 kb[4];
#pragma unroll
            for (int j = 0; j < 4; j++)
                kb[j] = *(const bf16x8*)&Ks[cur][(j * 16 + lrow) * 128 + (((kk * 4 + quad) ^ lrow) * 8)];
#pragma unroll
            for (int j = 0; j < 4; j++)
                sacc[j] = __builtin_amdgcn_mfma_f32_16x16x32_bf16(qf[kk], kb[j], sacc[j], 0, 0, 0);
        }
        __builtin_amdgcn_s_setprio(0);

        // scale + causal mask (only the diagonal tile kt==qt)
        const bool diag = (kt == qt);
#pragma unroll
        for (int j = 0; j < 4; j++)
#pragma unroll
            for (int r = 0; r < 4; r++) {
                float v = sacc[j][r] * scale;
                if (diag) {
                    int rowg = qbase + quad * 4 + r;
                    int colg = qt * 64 + j * 16 + lrow;
                    if (colg > rowg) v = -1e30f;
                }
                sacc[j][r] = v;
            }

        // online softmax per q-row (row lives on 16 lanes sharing quad)
        float alpha[4];
#pragma unroll
        for (int r = 0; r < 4; r++) {
            float mx = sacc[0][r];
#pragma unroll
            for (int j = 1; j < 4; j++) mx = fmaxf(mx, sacc[j][r]);
#pragma unroll
            for (int d = 1; d < 16; d <<= 1) mx = fmaxf(mx, __shfl_xor(mx, d, 16));
            float mnew = fmaxf(mrow[r], mx);
            float a = __expf(mrow[r] - mnew);
            mrow[r] = mnew;
            alpha[r] = a;
            float rs = 0.0f;
#pragma unroll
            for (int j = 0; j < 4; j++) {
                float p = __expf(sacc[j][r] - mnew);
                sacc[j][r] = p;
                rs += p;
            }
#pragma unroll
            for (int d = 1; d < 16; d <<= 1) rs += __shfl_xor(rs, d, 16);
            lsum[r] = lsum[r] * a + rs;
        }

        // rescale O
#pragma unroll
        for (int dj = 0; dj < 8; dj++)
#pragma unroll
            for (int r = 0; r < 4; r++) o[dj][r] *= alpha[r];

        // P (C-layout) -> per-wave LDS (conflict-free) -> A-operand fragments
#pragma unroll
        for (int j = 0; j < 4; j++)
#pragma unroll
            for (int r = 0; r < 4; r++)
                Pw[(quad * 4 + r) * PSTR + j * 16 + lrow] = __float2bfloat16(sacc[j][r]);
        __asm__ volatile("s_waitcnt lgkmcnt(0)" ::: "memory");   // same-wave write->read

        // O += P V : V^T fragments from swizzled LDS (B-layout: n=d on lanes)
        __builtin_amdgcn_s_setprio(1);
#pragma unroll
        for (int kk = 0; kk < 2; kk++) {
            bf16x8 pf = *(const bf16x8*)&Pw[lrow * PSTR + kk * 32 + quad * 8];
#pragma unroll
            for (int dj = 0; dj < 8; dj++) {
                int dr = dj * 16 + lrow;
                bf16x8 vb = *(const bf16x8*)&Vs[cur][dr * 64 + (((kk * 4 + quad) ^ (dr & 7)) * 8)];
                o[dj] = __builtin_amdgcn_mfma_f32_16x16x32_bf16(pf, vb, o[dj], 0, 0, 0);
            }
        }
        __builtin_amdgcn_s_setprio(0);

        __syncthreads();                            // staged data visible; reuse safe
        cur ^= 1;
    }

    // epilogue: un-normalized partial O + per-row (m, l)
#pragma unroll
    for (int dj = 0; dj < 8; dj++)
#pragma unroll
        for (int r = 0; r < 4; r++) {
            long rowg = qbase + quad * 4 + r;
            long col  = (long)h * HD + dj * 16 + lrow;
            Opart[(long)sp * SLEN * (NHEADS * HD) + rowg * (NHEADS * HD) + col] = o[dj][r];
        }
    if (lrow == 0) {
#pragma unroll
        for (int r = 0; r < 4; r++) {
            long rowg = qbase + quad * 4 + r;
            long mi = ((long)sp * SLEN + rowg) * (NHEADS * 2) + h * 2;
            Ml[mi]     = mrow[r];
            Ml[mi + 1] = lsum[r];
        }
    }
}

// ---------------- combine two key-split partials -> ctx bf16 ------------------------
__global__ __launch_bounds__(256) void attn_combine(const float* __restrict__ Opart,
                                                    const float* __restrict__ Ml,
                                                    bf16* __restrict__ Ctx) {
    long gid = (long)blockIdx.x * 256 + threadIdx.x;    // (row*16 + h)*16 + oct
    int oct = (int)(gid & 15);
    long rh = gid >> 4;
    int h = (int)(rh & 15);
    long row = rh >> 4;
    long mi0 = row * (NHEADS * 2) + h * 2;
    long mi1 = ((long)SLEN + row) * (NHEADS * 2) + h * 2;
    float m0 = Ml[mi0], l0 = Ml[mi0 + 1];
    float m1 = Ml[mi1], l1 = Ml[mi1 + 1];
    float m = fmaxf(m0, m1);
    float w0 = __expf(m0 - m), w1 = __expf(m1 - m);
    float inv = 1.0f / (w0 * l0 + w1 * l1);
    long base = row * (NHEADS * HD) + h * HD + oct * 8;
    float4 a0 = *(const float4*)&Opart[base];
    float4 b0 = *(const float4*)&Opart[base + 4];
    float4 a1 = *(const float4*)&Opart[(long)SLEN * (NHEADS * HD) + base];
    float4 b1 = *(const float4*)&Opart[(long)SLEN * (NHEADS * HD) + base + 4];
    float vals[8] = {w0*a0.x + w1*a1.x, w0*a0.y + w1*a1.y, w0*a0.z + w1*a1.z, w0*a0.w + w1*a1.w,
                     w0*b0.x + w1*b1.x, w0*b0.y + w1*b1.y, w0*b0.z + w1*b1.z, w0*b0.w + w1*b1.w};
    union { bf16x8 v; unsigned short u[8]; } pk;
#pragma unroll
    for (int e = 0; e < 8; e++) pk.u[e] = bf_bits(vals[e] * inv);
    *(bf16x8*)&Ctx[base] = pk.v;
}

// ---------------- split-K reduce: out += p0+p1+p2+p3 (residual already in out) ------
__global__ __launch_bounds__(256) void reduce4_kernel(const float* __restrict__ p,
                                                      float* __restrict__ out, long n) {
    long idx = ((long)blockIdx.x * 256 + threadIdx.x) * 4;
    if (idx >= n) return;
    float4 a = *(const float4*)&p[idx];
    float4 b = *(const float4*)&p[idx + n];
    float4 c = *(const float4*)&p[idx + 2 * n];
    float4 d = *(const float4*)&p[idx + 3 * n];
    float4 o = *(const float4*)&out[idx];
    o.x += a.x + b.x + c.x + d.x;
    o.y += a.y + b.y + c.y + d.y;
    o.z += a.z + b.z + c.z + d.z;
    o.w += a.w + b.w + c.w + d.w;
    *(float4*)&out[idx] = o;
}

// ------------------------------------------------------------------------------------
extern "C" void kernel_launch(void* const* d_in, const int* in_sizes, int n_in,
                              void* d_out, int out_size, void* d_ws, size_t ws_size,
                              hipStream_t stream) {
    const float* hidden = (const float*)d_in[0];
    const int*   pos    = (const int*)d_in[2];
    const float* n1w    = (const float*)d_in[3];
    const float* n2w    = (const float*)d_in[4];
    const float* Wq     = (const float*)d_in[5];
    const float* Wk     = (const float*)d_in[6];
    const float* Wv     = (const float*)d_in[7];
    const float* Wo     = (const float*)d_in[8];
    const float* Wg     = (const float*)d_in[9];
    const float* Wu     = (const float*)d_in[10];
    const float* Wd     = (const float*)d_in[11];
    float* out = (float*)d_out;

    char* ws = (char*)d_ws;
    const size_t MB = 1ull << 20;
    // Phase A:
    bf16* h    = (bf16*)(ws + 0);        // 8 MB  (also h2)
    bf16* qk   = (bf16*)(ws + 8  * MB);  // 10 MB [2048][2560] = q|k
    bf16* vt   = (bf16*)(ws + 18 * MB);  // 2 MB  [512][2048]  = V^T
    bf16* ctx  = (bf16*)(ws + 20 * MB);  // 8 MB
    bf16* wqk  = (bf16*)(ws + 28 * MB);  // 10 MB [2560][2048]; reused for wob (8 MB)
    bf16* wvb  = (bf16*)(ws + 38 * MB);  // 2 MB  [512][2048]
    float* opart = (float*)(ws + 40 * MB); // 32 MB [2][2048][2048] fp32 attn partials
    float* ml    = (float*)(ws + 72 * MB); // 0.5 MB [2][2048][16][2]
    // Phase B (reuses phase-A space once dead):
    bf16*  wg   = (bf16*)(ws + 8   * MB); // 32 MB (attn buffers dead)
    bf16*  wu   = (bf16*)(ws + 40  * MB); // 32 MB (opart dead after combine)
    bf16*  gate = (bf16*)(ws + 72  * MB); // 32 MB (ml dead; act written in-place)
    bf16*  wd   = (bf16*)(ws + 104 * MB); // 32 MB
    float* pbuf = (float*)(ws + 0);       // 67 MB (4 x 16.8 MB split-K partials;
                                          //        h/qk/wg/wu all dead by down-proj)
    bf16* wob = wqk;

    // 1) rmsnorm1 -> h
    rmsnorm_kernel<<<dim3(2048), dim3(256), 0, stream>>>(hidden, n1w, h);
    // 2) convert Wq|Wk into [2560][2048], Wv into its own block
    cvt_kernel<<<dim3(2048), dim3(256), 0, stream>>>(Wq, wqk,                2048L * 2048);
    cvt_kernel<<<dim3(512),  dim3(256), 0, stream>>>(Wk, wqk + 2048L * 2048, 512L * 2048);
    cvt_kernel<<<dim3(512),  dim3(256), 0, stream>>>(Wv, wvb,                512L * 2048);
    // 3) fused QK projection -> qk [2048][2560];  V^T = Wv @ h^T -> vt [512][2048]
    gemm_bt<0><<<dim3(20, 16), dim3(256), 0, stream>>>(h, wqk, qk, nullptr, 2048, 2560, 2048, 2048);
    gemm_bt<0><<<dim3(16, 4),  dim3(256), 0, stream>>>(wvb, h, vt, nullptr, 512, 2048, 2048, 2048);
    // 4) rope on q (cols 0..2047) and k (cols 2048..2559)
    rope_kernel<<<dim3(8192), dim3(256), 0, stream>>>(qk, pos, NHEADS, 2560);
    rope_kernel<<<dim3(2048), dim3(256), 0, stream>>>(qk + 2048, pos, NKV, 2560);
    // 5) flash attention (key-split x2) -> partials, then combine -> ctx
    flash_attn<<<dim3(64, 16), dim3(256), 0, stream>>>(qk, qk + 2048, vt, opart, ml);
    attn_combine<<<dim3(2048), dim3(256), 0, stream>>>(opart, ml, ctx);
    // 6) Wo projection + residual -> out (fp32)
    cvt_kernel<<<dim3(2048), dim3(256), 0, stream>>>(Wo, wob, 2048L * 2048);
    gemm_bt<1><<<dim3(16, 16), dim3(256), 0, stream>>>(ctx, wob, out, hidden, 2048, 2048, 2048, 2048);
    // 7) rmsnorm2 -> h
    rmsnorm_kernel<<<dim3(2048), dim3(256), 0, stream>>>(out, n2w, h);
    // 8) MLP: big GEMMs on the 256x256 8-phase kernel; silu fused into up-GEMM epi
    cvt_kernel<<<dim3(8192), dim3(256), 0, stream>>>(Wg, wg, 8192L * 2048);
    cvt_kernel<<<dim3(8192), dim3(256), 0, stream>>>(Wu, wu, 8192L * 2048);
    gemm256<0><<<dim3(32, 8), dim3(512), 0, stream>>>(h, wg, gate, nullptr, 2048, 8192, 2048, 2048);
    gemm256<3><<<dim3(32, 8), dim3(512), 0, stream>>>(h, wu, gate, gate,    2048, 8192, 2048, 2048);
    cvt_kernel<<<dim3(8192), dim3(256), 0, stream>>>(Wd, wd, 2048L * 8192);
    // 9) down-proj split-K=4 (8x8x4 = 256 blocks) -> fp32 partials, then out += sum
    gemm256<2><<<dim3(8, 8, 4), dim3(512), 0, stream>>>(gate, wd, pbuf, nullptr, 2048, 2048, 2048, 8192);
    reduce4_kernel<<<dim3(4096), dim3(256), 0, stream>>>(pbuf, out, 2048L * 2048);
    (void)in_sizes; (void)n_in; (void)out_size; (void)ws_size;
}

// Round 5
// 710.958 us; speedup vs baseline: 1.1879x; 1.0339x over previous
//
#include <hip/hip_runtime.h>
#include <hip/hip_bf16.h>
#include <math.h>

// Transformer block: rmsnorm -> fused QK GEMM + V^T GEMM -> rope -> causal flash attn
// (v6: key-split + dbuf gld_lds staging + SWAPPED-QK^T in-lane softmax) -> Wo +
// residual -> rmsnorm -> SwiGLU MLP (silu fused into up-GEMM epilogue) -> split-K
// down-proj + residual.

#define HIDDENC 2048
#define SLEN    2048
#define NHEADS  16
#define NKV     4
#define HD      128
#define INTERC  8192

typedef __attribute__((ext_vector_type(8))) short bf16x8;   // 8 x bf16 (4 VGPRs)
typedef __attribute__((ext_vector_type(4))) short bf16x4;   // 4 x bf16 (2 VGPRs)
typedef __attribute__((ext_vector_type(4))) float f32x4;
typedef __hip_bfloat16 bf16;

__device__ __forceinline__ void gld_lds16(const void* g, void* l) {
    __builtin_amdgcn_global_load_lds((const __attribute__((address_space(1))) void*)g,
                                     (__attribute__((address_space(3))) void*)l, 16, 0, 0);
}

__device__ __forceinline__ unsigned short bf_bits(float x) {
    bf16 t = __float2bfloat16(x);
    return *(unsigned short*)&t;
}
__device__ __forceinline__ float bits_f(short s) {
    bf16 b = *(bf16*)&s;
    return __bfloat162float(b);
}

#define SBAR      asm volatile("s_barrier" ::: "memory")
#define WAIT_VM4  asm volatile("s_waitcnt vmcnt(4)" ::: "memory")
#define WAIT_VM0  asm volatile("s_waitcnt vmcnt(0)" ::: "memory")

// ---------------- GEMM: C[M][N] = A[M][K'] @ B[N][K']^T, row stride lda -------------
// 128x128 tile, 2-phase. EPI=0: bf16 C.  EPI=1: fp32 C = acc + R.
template <int EPI>
__global__ __launch_bounds__(256) void gemm_bt(const bf16* __restrict__ A,
                                               const bf16* __restrict__ B,
                                               void* __restrict__ Cout,
                                               const float* __restrict__ R,
                                               int M, int N, int K, int lda) {
    constexpr int BM = 128, BN = 128, BK = 64;
    __shared__ bf16 As[BM * BK];
    __shared__ bf16 Bs[BN * BK];
    const int tid  = threadIdx.x;
    const int wave = tid >> 6;
    const int lane = tid & 63;
    const int wm = wave >> 1, wn = wave & 1;        // 2x2 waves, 64x64 each
    const long m0 = (long)blockIdx.y * BM;
    const long n0 = (long)blockIdx.x * BN;

    const int srow = wave * 8 + (lane >> 3);
    const int scol = (lane & 7) * 8;
    const bf16* Ag = A + (m0 + srow) * (long)lda + scol;
    const bf16* Bg = B + (n0 + srow) * (long)lda + scol;
    bf16* Asw = &As[(wave * 8) * BK];
    bf16* Bsw = &Bs[(wave * 8) * BK];

    f32x4 acc[4][4] = {};
    const int row = lane & 15;
    const int kq  = (lane >> 4) * 8;

    for (int k0 = 0; k0 < K; k0 += BK) {
#pragma unroll
        for (int t = 0; t < 4; t++) {
            gld_lds16(Ag + (long)(t * 32) * lda + k0, Asw + t * 32 * BK);
            gld_lds16(Bg + (long)(t * 32) * lda + k0, Bsw + t * 32 * BK);
        }
        __syncthreads();
#pragma unroll
        for (int kk = 0; kk < BK; kk += 32) {
            bf16x8 af[4], bfr[4];
#pragma unroll
            for (int i = 0; i < 4; i++)
                af[i] = *(const bf16x8*)&As[(wm * 64 + i * 16 + row) * BK + kk + kq];
#pragma unroll
            for (int j = 0; j < 4; j++)
                bfr[j] = *(const bf16x8*)&Bs[(wn * 64 + j * 16 + row) * BK + kk + kq];
#pragma unroll
            for (int i = 0; i < 4; i++)
#pragma unroll
                for (int j = 0; j < 4; j++)
                    acc[i][j] = __builtin_amdgcn_mfma_f32_16x16x32_bf16(af[i], bfr[j], acc[i][j], 0, 0, 0);
        }
        __syncthreads();
    }

    const int quad = lane >> 4;
#pragma unroll
    for (int i = 0; i < 4; i++)
#pragma unroll
        for (int j = 0; j < 4; j++)
#pragma unroll
            for (int r = 0; r < 4; r++) {
                long rr = m0 + wm * 64 + i * 16 + quad * 4 + r;   // C/D: row = quad*4+reg
                long cc = n0 + wn * 64 + j * 16 + (lane & 15);    //      col = lane&15
                float v = acc[i][j][r];
                if (EPI == 0) {
                    ((bf16*)Cout)[rr * N + cc] = __float2bfloat16(v);
                } else {
                    ((float*)Cout)[rr * N + cc] = v + R[rr * N + cc];
                }
            }
}

// ---------------- GEMM 256x256, 8-phase counted-vmcnt schedule ----------------------
// C[M][N] = A[M][K'] @ B[N][K']^T (per split-K slice). 512 thr = 2x4 waves, each owns
// a 128x64 output tile. BK=64, dbuf LDS 128 KiB. LDS tiles stored with 16B-granule
// XOR swizzle (g ^ row&7) via pre-swizzled GLOBAL source + linear global_load_lds dest
// (rule #21); ds_read_b128 fragment loads apply the same XOR -> conflict-free.
// Per K-tile: 4 phases, each = {ds_read subtile | stage prefetch | bar | MFMA quadrant
// (16x) under setprio | bar}; vmcnt(4) once per tile (B of tile t+2 stays in flight).
// EPI=0: bf16 C.  EPI=2: fp32 partial at Cout + z*M*N.  EPI=3: bf16 silu(G)*acc.
template <int EPI>
__global__ __launch_bounds__(512) void gemm256(const bf16* __restrict__ A,
                                               const bf16* __restrict__ B,
                                               void* __restrict__ Cout,
                                               const bf16* __restrict__ Gg,
                                               int M, int N, int K, int lda) {
    __shared__ __align__(16) bf16 smem[2][2][256 * 64];   // [dbuf][A=0/B=1][256 rows][64]
    const int tid  = threadIdx.x;
    const int wave = tid >> 6, lane = tid & 63;
    const int wm = wave >> 2, wn = wave & 3;              // 2 x 4 waves
    const int quad = lane >> 4, lrow = lane & 15;
    const long m0 = (long)blockIdx.y * 256;
    const long n0 = (long)blockIdx.x * 256;
    const long kofs = (long)blockIdx.z * K;

    // staging: thread covers (row = rr*64 + srow, one 16B granule). LDS dest is linear
    // (tid*16B); the global source granule is pre-swizzled so the read-side XOR matches.
    const int srow  = tid >> 3;                           // 0..63
    const int gphys = tid & 7;
    const int glog  = gphys ^ (srow & 7);
    const bf16* Ag = A + (m0 + srow) * (long)lda + kofs + glog * 8;
    const bf16* Bg = B + (n0 + srow) * (long)lda + kofs + glog * 8;

    auto stageA = [&](int tt) {                           // full A tile of K-tile tt (4 ld)
#pragma unroll
        for (int rr = 0; rr < 4; rr++)
            gld_lds16(Ag + ((long)tt << 6) + (long)(rr * 64) * lda,
                      &smem[tt & 1][0][tid * 8 + rr * 4096]);
    };
    auto stageB = [&](int tt, int hh) {                   // half B tile (2 ld)
#pragma unroll
        for (int r2 = 0; r2 < 2; r2++) {
            int rr = hh * 2 + r2;
            gld_lds16(Bg + ((long)tt << 6) + (long)(rr * 64) * lda,
                      &smem[tt & 1][1][tid * 8 + rr * 4096]);
        }
    };

    f32x4 acc[8][4] = {};
    const int swz = (quad ^ (lrow & 7)) * 8;              // ks=0 granule elem offset
    const int NT = K >> 6;

    // prologue: A(0)+B(0) must arrive; B(1) (4 loads, newest) stays in flight.
    stageA(0);
    stageB(0, 0); stageB(0, 1);
    if (NT > 1) { stageB(1, 0); stageB(1, 1); }
    WAIT_VM4;
    SBAR;

    for (int t = 0; t < NT; ++t) {
        const bf16* smA = &smem[t & 1][0][0];
        const bf16* smB = &smem[t & 1][1][0];
        bf16x8 bq[4][2], aq[2][2];

        // ---- phase 0: all B frags + A quadrant 0; stage A(t+1) into other buffer ----
#pragma unroll
        for (int n = 0; n < 4; n++)
#pragma unroll
            for (int ks = 0; ks < 2; ks++)
                bq[n][ks] = *(const bf16x8*)&smB[(wn * 64 + n * 16 + lrow) * 64 + (swz ^ (ks * 32))];
#pragma unroll
        for (int i = 0; i < 2; i++)
#pragma unroll
            for (int ks = 0; ks < 2; ks++)
                aq[i][ks] = *(const bf16x8*)&smA[(wm * 128 + i * 16 + lrow) * 64 + (swz ^ (ks * 32))];
        if (t + 1 < NT) stageA(t + 1);
        SBAR;
        __builtin_amdgcn_s_setprio(1);
#pragma unroll
        for (int i = 0; i < 2; i++)
#pragma unroll
            for (int n = 0; n < 4; n++) {
                acc[i][n] = __builtin_amdgcn_mfma_f32_16x16x32_bf16(aq[i][0], bq[n][0], acc[i][n], 0, 0, 0);
                acc[i][n] = __builtin_amdgcn_mfma_f32_16x16x32_bf16(aq[i][1], bq[n][1], acc[i][n], 0, 0, 0);
            }
        __builtin_amdgcn_s_setprio(0);
        SBAR;

        // ---- phases 1..3: A quadrants 1..3; stage B(t+2) halves; boundary vmcnt ----
#pragma unroll
        for (int q = 1; q < 4; q++) {
#pragma unroll
            for (int i = 0; i < 2; i++)
#pragma unroll
                for (int ks = 0; ks < 2; ks++)
                    aq[i][ks] = *(const bf16x8*)&smA[(wm * 128 + (q * 2 + i) * 16 + lrow) * 64 + (swz ^ (ks * 32))];
            if (q == 1) { if (t + 2 < NT) stageB(t + 2, 0); }
            if (q == 2) { if (t + 2 < NT) stageB(t + 2, 1); }
            SBAR;
            __builtin_amdgcn_s_setprio(1);
#pragma unroll
            for (int i = 0; i < 2; i++)
#pragma unroll
                for (int n = 0; n < 4; n++) {
                    acc[q * 2 + i][n] = __builtin_amdgcn_mfma_f32_16x16x32_bf16(aq[i][0], bq[n][0], acc[q * 2 + i][n], 0, 0, 0);
                    acc[q * 2 + i][n] = __builtin_amdgcn_mfma_f32_16x16x32_bf16(aq[i][1], bq[n][1], acc[q * 2 + i][n], 0, 0, 0);
                }
            __builtin_amdgcn_s_setprio(0);
            if (q == 3) {
                if (t + 2 < NT) { WAIT_VM4; } else { WAIT_VM0; }
            }
            SBAR;
        }
    }

    // epilogue: C/D row = quad*4+reg, col = lane&15
#pragma unroll
    for (int i = 0; i < 8; i++)
#pragma unroll
        for (int n = 0; n < 4; n++)
#pragma unroll
            for (int r = 0; r < 4; r++) {
                long rr = m0 + wm * 128 + i * 16 + quad * 4 + r;
                long cc = n0 + wn * 64 + n * 16 + lrow;
                float v = acc[i][n][r];
                if (EPI == 0) {
                    ((bf16*)Cout)[rr * N + cc] = __float2bfloat16(v);
                } else if (EPI == 2) {
                    ((float*)Cout)[(long)blockIdx.z * M * N + rr * N + cc] = v;
                } else {                                  // EPI==3: act = silu(gate)*up
                    float g = __bfloat162float(Gg[rr * N + cc]);
                    float sg = g / (1.0f + __expf(-g));
                    ((bf16*)Cout)[rr * N + cc] = __float2bfloat16(sg * v);
                }
            }
}

// ---------------- RMSNorm: one block per row, fp32 in -> bf16 out -------------------
__global__ __launch_bounds__(256) void rmsnorm_kernel(const float* __restrict__ x,
                                                      const float* __restrict__ w,
                                                      bf16* __restrict__ out) {
    const int row = blockIdx.x;
    const int tid = threadIdx.x;
    const float* xr = x + (long)row * HIDDENC;
    float4 a = *(const float4*)&xr[tid * 8];
    float4 b = *(const float4*)&xr[tid * 8 + 4];
    float ss = a.x*a.x + a.y*a.y + a.z*a.z + a.w*a.w + b.x*b.x + b.y*b.y + b.z*b.z + b.w*b.w;
#pragma unroll
    for (int d = 1; d < 64; d <<= 1) ss += __shfl_xor(ss, d, 64);
    __shared__ float wsum[4];
    if ((tid & 63) == 0) wsum[tid >> 6] = ss;
    __syncthreads();
    ss = wsum[0] + wsum[1] + wsum[2] + wsum[3];
    float sc = rsqrtf(ss * (1.0f / HIDDENC) + 1e-6f);
    float4 wa = *(const float4*)&w[tid * 8];
    float4 wb = *(const float4*)&w[tid * 8 + 4];
    float vals[8] = {a.x*wa.x, a.y*wa.y, a.z*wa.z, a.w*wa.w,
                     b.x*wb.x, b.y*wb.y, b.z*wb.z, b.w*wb.w};
    union { bf16x8 v; unsigned short u[8]; } pk;
#pragma unroll
    for (int e = 0; e < 8; e++) pk.u[e] = bf_bits(vals[e] * sc);
    *(bf16x8*)&out[(long)row * HIDDENC + tid * 8] = pk.v;
}

// ---------------- fp32 -> bf16 convert (weights) ------------------------------------
__global__ __launch_bounds__(256) void cvt_kernel(const float* __restrict__ in,
                                                  bf16* __restrict__ out, long n) {
    long idx = ((long)blockIdx.x * 256 + threadIdx.x) * 8;
    if (idx >= n) return;
    float4 a = *(const float4*)&in[idx];
    float4 b = *(const float4*)&in[idx + 4];
    float vals[8] = {a.x, a.y, a.z, a.w, b.x, b.y, b.z, b.w};
    union { bf16x8 v; unsigned short u[8]; } pk;
#pragma unroll
    for (int e = 0; e < 8; e++) pk.u[e] = bf_bits(vals[e]);
    *(bf16x8*)&out[idx] = pk.v;
}

// ---------------- RoPE in-place on bf16 [S][rowstride], heads at col h*HD -----------
__global__ __launch_bounds__(256) void rope_kernel(bf16* __restrict__ x,
                                                   const int* __restrict__ pos,
                                                   int nheads, int rowstride) {
    long gid = (long)blockIdx.x * 256 + threadIdx.x;
    int i = gid & 63;
    long t = gid >> 6;
    int h = (int)(t % nheads);
    long s = t / nheads;
    if (s >= SLEN) return;
    float inv = __expf(-(float)i * 0.14391156516779195f);   // ln(10000)/64
    float f = (float)pos[s] * inv;
    float sn, c;
    sincosf(f, &sn, &c);
    bf16* p = x + s * (long)rowstride + h * HD + i;
    float x1 = __bfloat162float(p[0]);
    float x2 = __bfloat162float(p[64]);
    p[0]  = __float2bfloat16(x1 * c - x2 * sn);
    p[64] = __float2bfloat16(x2 * c + x1 * sn);
}

// ---------------- causal flash attention v6 -----------------------------------------
// grid (64, 16): bx -> (qt = 31-(bx>>1), sp = bx&1). Block handles kt = sp, sp+2, ...
// <= qt -> partial O (fp32, un-normalized) + (m, l); combine kernel merges splits.
// SWAPPED QK^T: S^T = mfma(K, Q) puts q on lanes (lane lrow owns q-row qbase+lrow,
// 16 keys in regs, row spread over 4 quads) -> softmax = in-lane tree + 2 shfl_xor
// (vs 32 bpermutes in v5). P store = 4x ds_write_b64. PV unchanged.
__global__ __launch_bounds__(256) void flash_attn(const bf16* __restrict__ Q,   // [S][2560]
                                                  const bf16* __restrict__ Kb,  // +2048 col
                                                  const bf16* __restrict__ VT,  // [512][2048]
                                                  float* __restrict__ Opart,    // [2][S][2048]
                                                  float* __restrict__ Ml) {     // [2][S][16][2]
    constexpr int QSTR = 2560, PSTR = 68, BKEY = 64;
    __shared__ bf16 Ks[2][64 * 128];                // swizzled [key][d], 2 x 16 KB
    __shared__ bf16 Vs[2][128 * 64];                // swizzled [d][key], 2 x 16 KB
    __shared__ bf16 Ps[4][16 * PSTR];               // per-wave P [16 q][64 keys + pad]
    const int qt  = 31 - (int)(blockIdx.x >> 1);    // heavy tiles dispatched first
    const int sp  = blockIdx.x & 1;                 // key split
    const int h   = blockIdx.y;
    const int kvh = h >> 2;
    const int tid = threadIdx.x;
    const int wave = tid >> 6, lane = tid & 63;
    const int quad = lane >> 4, lrow = lane & 15;
    const int qbase = qt * 64 + wave * 16;

    // resident Q fragments (used as MFMA B-operand: n=q=lrow, k=quad*8+e)
    bf16x8 qf[4];
#pragma unroll
    for (int kk = 0; kk < 4; kk++)
        qf[kk] = *(const bf16x8*)&Q[(long)(qbase + lrow) * QSTR + h * HD + kk * 32 + quad * 8];

    f32x4 o[8] = {};
    float m_l = -1e30f, l_l = 0.0f;                 // per-lane: q-row qbase+lrow

    const float scale = 0.08838834764831845f;       // 1/sqrt(128)
    const bf16* Kh  = Kb + kvh * HD;                // [key][2560]
    const bf16* VTh = VT + (long)(kvh * HD) * SLEN; // [128][2048]
    bf16* Pw = Ps[wave];

    // staging geometry (16B granules, linear LDS dest = id*16B, pre-swizzled source):
    // K: id = rd*256+tid; row = rd*16 + (tid>>4); g = tid&15; glog = g ^ (row&15)
    // V: id = rd*256+tid; d   = rd*32 + (tid>>3); g = tid&7;  glog = g ^ (d&7)
    const int glogK = (tid & 15) ^ ((tid >> 4) & 15);
    const int glogV = (tid & 7) ^ ((tid >> 3) & 7);
    const bf16* KgB = Kh + (long)(tid >> 4) * QSTR + glogK * 8;
    const bf16* VgB = VTh + (long)(tid >> 3) * SLEN + glogV * 8;

    auto stage = [&](int kt, int b) {
#pragma unroll
        for (int rd = 0; rd < 4; rd++)
            gld_lds16(KgB + (long)(kt * BKEY + rd * 16) * QSTR,
                      &Ks[b][(rd * 256 + tid) * 8]);
#pragma unroll
        for (int rd = 0; rd < 4; rd++)
            gld_lds16(VgB + (long)(rd * 32) * SLEN + kt * BKEY,
                      &Vs[b][(rd * 256 + tid) * 8]);
    };

    int cur = 0;
    stage(sp, 0);
    WAIT_VM0;
    __syncthreads();

    for (int kt = sp; kt <= qt; kt += 2) {
        if (kt + 2 <= qt) stage(kt + 2, cur ^ 1);   // prefetch; latency hides under compute

        // S^T = K Q^T : sacc[j][r] = S[q = qbase+lrow][key = kt*64 + j*16 + quad*4 + r]
        f32x4 sacc[4] = {};
        __builtin_amdgcn_s_setprio(1);
#pragma unroll
        for (int kk = 0; kk < 4; kk++) {
            bf16x8 kb[4];
#pragma unroll
            for (int j = 0; j < 4; j++)
                kb[j] = *(const bf16x8*)&Ks[cur][(j * 16 + lrow) * 128 + (((kk * 4 + quad) ^ lrow) * 8)];
#pragma unroll
            for (int j = 0; j < 4; j++)
                sacc[j] = __builtin_amdgcn_mfma_f32_16x16x32_bf16(kb[j], qf[kk], sacc[j], 0, 0, 0);
        }
        __builtin_amdgcn_s_setprio(0);

        // scale + causal mask (only the diagonal tile kt==qt)
        const bool diag = (kt == qt);
        const int qg = qbase + lrow;
#pragma unroll
        for (int j = 0; j < 4; j++)
#pragma unroll
            for (int r = 0; r < 4; r++) {
                float v = sacc[j][r] * scale;
                if (diag) {
                    int keyg = qt * 64 + j * 16 + quad * 4 + r;
                    if (keyg > qg) v = -1e30f;
                }
                sacc[j][r] = v;
            }

        // online softmax: in-lane tree over 16 keys + 2-step cross-quad xor reduce
        float t0 = fmaxf(fmaxf(sacc[0][0], sacc[0][1]), fmaxf(sacc[0][2], sacc[0][3]));
        float t1 = fmaxf(fmaxf(sacc[1][0], sacc[1][1]), fmaxf(sacc[1][2], sacc[1][3]));
        float t2 = fmaxf(fmaxf(sacc[2][0], sacc[2][1]), fmaxf(sacc[2][2], sacc[2][3]));
        float t3 = fmaxf(fmaxf(sacc[3][0], sacc[3][1]), fmaxf(sacc[3][2], sacc[3][3]));
        float mx = fmaxf(fmaxf(t0, t1), fmaxf(t2, t3));
        mx = fmaxf(mx, __shfl_xor(mx, 16, 64));
        mx = fmaxf(mx, __shfl_xor(mx, 32, 64));
        float mnew = fmaxf(m_l, mx);
        float alpha = __expf(m_l - mnew);
        m_l = mnew;
#pragma unroll
        for (int j = 0; j < 4; j++)
#pragma unroll
            for (int r = 0; r < 4; r++)
                sacc[j][r] = __expf(sacc[j][r] - mnew);
        float s0 = (sacc[0][0] + sacc[0][1]) + (sacc[0][2] + sacc[0][3]);
        float s1 = (sacc[1][0] + sacc[1][1]) + (sacc[1][2] + sacc[1][3]);
        float s2 = (sacc[2][0] + sacc[2][1]) + (sacc[2][2] + sacc[2][3]);
        float s3 = (sacc[3][0] + sacc[3][1]) + (sacc[3][2] + sacc[3][3]);
        float rs = (s0 + s1) + (s2 + s3);
        rs += __shfl_xor(rs, 16, 64);
        rs += __shfl_xor(rs, 32, 64);
        l_l = l_l * alpha + rs;

        // O rows are q = quad*4+r (C-layout of PV): fetch alpha from lane lrow'=quad*4+r
        float aR[4];
#pragma unroll
        for (int r = 0; r < 4; r++) aR[r] = __shfl(alpha, quad * 4 + r, 16);
#pragma unroll
        for (int dj = 0; dj < 8; dj++)
#pragma unroll
            for (int r = 0; r < 4; r++) o[dj][r] *= aR[r];

        // P[q = lrow][key = j*16 + quad*4 + r]: 4 contiguous keys -> ds_write_b64
#pragma unroll
        for (int j = 0; j < 4; j++) {
            union { bf16x4 v; unsigned short u[4]; } pk4;
#pragma unroll
            for (int r = 0; r < 4; r++) pk4.u[r] = bf_bits(sacc[j][r]);
            *(bf16x4*)&Pw[lrow * PSTR + j * 16 + quad * 4] = pk4.v;
        }
        __asm__ volatile("s_waitcnt lgkmcnt(0)" ::: "memory");   // same-wave write->read

        // O += P V : A = P (m=q, k=key), B = V^T fragments from swizzled LDS (n=d)
        __builtin_amdgcn_s_setprio(1);
#pragma unroll
        for (int kk = 0; kk < 2; kk++) {
            bf16x8 pf = *(const bf16x8*)&Pw[lrow * PSTR + kk * 32 + quad * 8];
#pragma unroll
            for (int dj = 0; dj < 8; dj++) {
                int dr = dj * 16 + lrow;
                bf16x8 vb = *(const bf16x8*)&Vs[cur][dr * 64 + (((kk * 4 + quad) ^ (dr & 7)) * 8)];
                o[dj] = __builtin_amdgcn_mfma_f32_16x16x32_bf16(pf, vb, o[dj], 0, 0, 0);
            }
        }
        __builtin_amdgcn_s_setprio(0);

        __syncthreads();                            // staged data visible; reuse safe
        cur ^= 1;
    }

    // epilogue: un-normalized partial O + per-row (m, l)
#pragma unroll
    for (int dj = 0; dj < 8; dj++)
#pragma unroll
        for (int r = 0; r < 4; r++) {
            long rowg = qbase + quad * 4 + r;
            long col  = (long)h * HD + dj * 16 + lrow;
            Opart[(long)sp * SLEN * (NHEADS * HD) + rowg * (NHEADS * HD) + col] = o[dj][r];
        }
    if (quad == 0) {                                // lanes 0..15 hold (m,l) for q=qbase+lrow
        long rowg = qbase + lrow;
        long mi = ((long)sp * SLEN + rowg) * (NHEADS * 2) + h * 2;
        Ml[mi]     = m_l;
        Ml[mi + 1] = l_l;
    }
}

// ---------------- combine two key-split partials -> ctx bf16 ------------------------
__global__ __launch_bounds__(256) void attn_combine(const float* __restrict__ Opart,
                                                    const float* __restrict__ Ml,
                                                    bf16* __restrict__ Ctx) {
    long gid = (long)blockIdx.x * 256 + threadIdx.x;    // (row*16 + h)*16 + oct
    int oct = (int)(gid & 15);
    long rh = gid >> 4;
    int h = (int)(rh & 15);
    long row = rh >> 4;
    long mi0 = row * (NHEADS * 2) + h * 2;
    long mi1 = ((long)SLEN + row) * (NHEADS * 2) + h * 2;
    float m0 = Ml[mi0], l0 = Ml[mi0 + 1];
    float m1 = Ml[mi1], l1 = Ml[mi1 + 1];
    float m = fmaxf(m0, m1);
    float w0 = __expf(m0 - m), w1 = __expf(m1 - m);
    float inv = 1.0f / (w0 * l0 + w1 * l1);
    long base = row * (NHEADS * HD) + h * HD + oct * 8;
    float4 a0 = *(const float4*)&Opart[base];
    float4 b0 = *(const float4*)&Opart[base + 4];
    float4 a1 = *(const float4*)&Opart[(long)SLEN * (NHEADS * HD) + base];
    float4 b1 = *(const float4*)&Opart[(long)SLEN * (NHEADS * HD) + base + 4];
    float vals[8] = {w0*a0.x + w1*a1.x, w0*a0.y + w1*a1.y, w0*a0.z + w1*a1.z, w0*a0.w + w1*a1.w,
                     w0*b0.x + w1*b1.x, w0*b0.y + w1*b1.y, w0*b0.z + w1*b1.z, w0*b0.w + w1*b1.w};
    union { bf16x8 v; unsigned short u[8]; } pk;
#pragma unroll
    for (int e = 0; e < 8; e++) pk.u[e] = bf_bits(vals[e] * inv);
    *(bf16x8*)&Ctx[base] = pk.v;
}

// ---------------- split-K reduce: out += p0+p1+p2+p3 (residual already in out) ------
__global__ __launch_bounds__(256) void reduce4_kernel(const float* __restrict__ p,
                                                      float* __restrict__ out, long n) {
    long idx = ((long)blockIdx.x * 256 + threadIdx.x) * 4;
    if (idx >= n) return;
    float4 a = *(const float4*)&p[idx];
    float4 b = *(const float4*)&p[idx + n];
    float4 c = *(const float4*)&p[idx + 2 * n];
    float4 d = *(const float4*)&p[idx + 3 * n];
    float4 o = *(const float4*)&out[idx];
    o.x += a.x + b.x + c.x + d.x;
    o.y += a.y + b.y + c.y + d.y;
    o.z += a.z + b.z + c.z + d.z;
    o.w += a.w + b.w + c.w + d.w;
    *(float4*)&out[idx] = o;
}

// ------------------------------------------------------------------------------------
extern "C" void kernel_launch(void* const* d_in, const int* in_sizes, int n_in,
                              void* d_out, int out_size, void* d_ws, size_t ws_size,
                              hipStream_t stream) {
    const float* hidden = (const float*)d_in[0];
    const int*   pos    = (const int*)d_in[2];
    const float* n1w    = (const float*)d_in[3];
    const float* n2w    = (const float*)d_in[4];
    const float* Wq     = (const float*)d_in[5];
    const float* Wk     = (const float*)d_in[6];
    const float* Wv     = (const float*)d_in[7];
    const float* Wo     = (const float*)d_in[8];
    const float* Wg     = (const float*)d_in[9];
    const float* Wu     = (const float*)d_in[10];
    const float* Wd     = (const float*)d_in[11];
    float* out = (float*)d_out;

    char* ws = (char*)d_ws;
    const size_t MB = 1ull << 20;
    // Phase A:
    bf16* h    = (bf16*)(ws + 0);        // 8 MB  (also h2)
    bf16* qk   = (bf16*)(ws + 8  * MB);  // 10 MB [2048][2560] = q|k
    bf16* vt   = (bf16*)(ws + 18 * MB);  // 2 MB  [512][2048]  = V^T
    bf16* ctx  = (bf16*)(ws + 20 * MB);  // 8 MB
    bf16* wqk  = (bf16*)(ws + 28 * MB);  // 10 MB [2560][2048]; reused for wob (8 MB)
    bf16* wvb  = (bf16*)(ws + 38 * MB);  // 2 MB  [512][2048]
    float* opart = (float*)(ws + 40 * MB); // 32 MB [2][2048][2048] fp32 attn partials
    float* ml    = (float*)(ws + 72 * MB); // 0.5 MB [2][2048][16][2]
    // Phase B (reuses phase-A space once dead):
    bf16*  wg   = (bf16*)(ws + 8   * MB); // 32 MB (attn buffers dead)
    bf16*  wu   = (bf16*)(ws + 40  * MB); // 32 MB (opart dead after combine)
    bf16*  gate = (bf16*)(ws + 72  * MB); // 32 MB (ml dead; act written in-place)
    bf16*  wd   = (bf16*)(ws + 104 * MB); // 32 MB
    float* pbuf = (float*)(ws + 0);       // 67 MB (4 x 16.8 MB split-K partials;
                                          //        h/qk/wg/wu all dead by down-proj)
    bf16* wob = wqk;

    // 1) rmsnorm1 -> h
    rmsnorm_kernel<<<dim3(2048), dim3(256), 0, stream>>>(hidden, n1w, h);
    // 2) convert Wq|Wk into [2560][2048], Wv into its own block
    cvt_kernel<<<dim3(2048), dim3(256), 0, stream>>>(Wq, wqk,                2048L * 2048);
    cvt_kernel<<<dim3(512),  dim3(256), 0, stream>>>(Wk, wqk + 2048L * 2048, 512L * 2048);
    cvt_kernel<<<dim3(512),  dim3(256), 0, stream>>>(Wv, wvb,                512L * 2048);
    // 3) fused QK projection -> qk [2048][2560];  V^T = Wv @ h^T -> vt [512][2048]
    gemm_bt<0><<<dim3(20, 16), dim3(256), 0, stream>>>(h, wqk, qk, nullptr, 2048, 2560, 2048, 2048);
    gemm_bt<0><<<dim3(16, 4),  dim3(256), 0, stream>>>(wvb, h, vt, nullptr, 512, 2048, 2048, 2048);
    // 4) rope on q (cols 0..2047) and k (cols 2048..2559)
    rope_kernel<<<dim3(8192), dim3(256), 0, stream>>>(qk, pos, NHEADS, 2560);
    rope_kernel<<<dim3(2048), dim3(256), 0, stream>>>(qk + 2048, pos, NKV, 2560);
    // 5) flash attention (key-split x2) -> partials, then combine -> ctx
    flash_attn<<<dim3(64, 16), dim3(256), 0, stream>>>(qk, qk + 2048, vt, opart, ml);
    attn_combine<<<dim3(2048), dim3(256), 0, stream>>>(opart, ml, ctx);
    // 6) Wo projection + residual -> out (fp32)
    cvt_kernel<<<dim3(2048), dim3(256), 0, stream>>>(Wo, wob, 2048L * 2048);
    gemm_bt<1><<<dim3(16, 16), dim3(256), 0, stream>>>(ctx, wob, out, hidden, 2048, 2048, 2048, 2048);
    // 7) rmsnorm2 -> h
    rmsnorm_kernel<<<dim3(2048), dim3(256), 0, stream>>>(out, n2w, h);
    // 8) MLP: big GEMMs on the 256x256 8-phase kernel; silu fused into up-GEMM epi
    cvt_kernel<<<dim3(8192), dim3(256), 0, stream>>>(Wg, wg, 8192L * 2048);
    cvt_kernel<<<dim3(8192), dim3(256), 0, stream>>>(Wu, wu, 8192L * 2048);
    gemm256<0><<<dim3(32, 8), dim3(512), 0, stream>>>(h, wg, gate, nullptr, 2048, 8192, 2048, 2048);
    gemm256<3><<<dim3(32, 8), dim3(512), 0, stream>>>(h, wu, gate, gate,    2048, 8192, 2048, 2048);
    cvt_kernel<<<dim3(8192), dim3(256), 0, stream>>>(Wd, wd, 2048L * 8192);
    // 9) down-proj split-K=4 (8x8x4 = 256 blocks) -> fp32 partials, then out += sum
    gemm256<2><<<dim3(8, 8, 4), dim3(512), 0, stream>>>(gate, wd, pbuf, nullptr, 2048, 2048, 2048, 8192);
    reduce4_kernel<<<dim3(4096), dim3(256), 0, stream>>>(pbuf, out, 2048L * 2048);
    (void)in_sizes; (void)n_in; (void)out_size; (void)ws_size;
}